// Round 1
// baseline (540.619 us; speedup 1.0000x reference)
//
#include <hip/hip_runtime.h>

#define D_MODEL 1024
#define D_STATE 16
#define M_ROWS  4096   // B*L
#define SEQ_L   1024
#define NBATCH  4

typedef __bf16 bf16x8 __attribute__((ext_vector_type(8)));
typedef float  f32x4  __attribute__((ext_vector_type(4)));
typedef unsigned short us8 __attribute__((ext_vector_type(8)));

__device__ __forceinline__ unsigned short f2bf(float f) {
  unsigned int u = __builtin_bit_cast(unsigned int, f);
  u += 0x7fffu + ((u >> 16) & 1u);           // RNE
  return (unsigned short)(u >> 16);
}
__device__ __forceinline__ float bf2f(unsigned short b) {
  unsigned int u = ((unsigned int)b) << 16;
  return __builtin_bit_cast(float, u);
}
__device__ __forceinline__ float load_elem(const void* p, size_t i, int isbf) {
  if (isbf) return bf2f(((const unsigned short*)p)[i]);
  return ((const float*)p)[i];
}

// ---------------- dtype detection ----------------
// Sample even-indexed uint16s of x_in. If data is bf16, every such u16 is a
// bf16 of N(0,1): exponent field in [100,135] essentially always. If data is
// fp32, even u16s are low mantissa bits: exponent field ~uniform (~14% in range).
__global__ void detect_kernel(const unsigned short* __restrict__ x, int* __restrict__ flag) {
  __shared__ int cnt;
  if (threadIdx.x == 0) cnt = 0;
  __syncthreads();
  unsigned int v = x[2 * threadIdx.x];
  unsigned int e = (v >> 7) & 0xFFu;
  int ok = (e >= 100u && e <= 135u) ? 1 : 0;
  atomicAdd(&cnt, ok);
  __syncthreads();
  if (threadIdx.x == 0) *flag = (cnt >= 128) ? 1 : 0;
}

// ---------------- canonicalize x_in -> fp32 ----------------
__global__ void convert_x_kernel(const void* __restrict__ src, float* __restrict__ dst,
                                 const int* __restrict__ flag) {
  int c = blockIdx.x * blockDim.x + threadIdx.x;  // chunk of 8 elems
  int isbf = *flag;
  float o[8];
  if (isbf) {
    uint4 v = ((const uint4*)src)[c];
    o[0] = bf2f((unsigned short)(v.x & 0xffffu)); o[1] = bf2f((unsigned short)(v.x >> 16));
    o[2] = bf2f((unsigned short)(v.y & 0xffffu)); o[3] = bf2f((unsigned short)(v.y >> 16));
    o[4] = bf2f((unsigned short)(v.z & 0xffffu)); o[5] = bf2f((unsigned short)(v.z >> 16));
    o[6] = bf2f((unsigned short)(v.w & 0xffffu)); o[7] = bf2f((unsigned short)(v.w >> 16));
  } else {
    float4 a = ((const float4*)src)[2 * c];
    float4 b = ((const float4*)src)[2 * c + 1];
    o[0]=a.x; o[1]=a.y; o[2]=a.z; o[3]=a.w; o[4]=b.x; o[5]=b.y; o[6]=b.z; o[7]=b.w;
  }
  float4* d = (float4*)dst;
  d[2*c]   = make_float4(o[0], o[1], o[2], o[3]);
  d[2*c+1] = make_float4(o[4], o[5], o[6], o[7]);
}

// ---------------- canonicalize small vectors ----------------
__global__ void convert_smalls_kernel(const void* b_dt, const void* A_log, const void* Dp,
                                      const void* ln_g, const void* ln_b,
                                      float* o_bdt, float* o_alog, float* o_dp,
                                      float* o_lng, float* o_lnb,
                                      const int* __restrict__ flag) {
  int g = blockIdx.x * blockDim.x + threadIdx.x;  // 0..20479
  int isbf = *flag;
  if (g < 1024)              o_bdt[g]          = load_elem(b_dt, g, isbf);
  else if (g < 17408)        o_alog[g - 1024]  = load_elem(A_log, g - 1024, isbf);
  else if (g < 18432)        o_dp[g - 17408]   = load_elem(Dp, g - 17408, isbf);
  else if (g < 19456)        o_lng[g - 18432]  = load_elem(ln_g, g - 18432, isbf);
  else                       o_lnb[g - 19456]  = load_elem(ln_b, g - 19456, isbf);
}

// ---------------- weight transpose: (K=1024 x ncols) -> bf16 (nrows_dst x 1024) ----------------
__global__ void transpose_w_kernel(const void* __restrict__ src, unsigned short* __restrict__ dst,
                                   int ncols, const int* __restrict__ flag) {
  __shared__ float tile[32][33];
  int tx = threadIdx.x, ty = threadIdx.y;   // 32 x 8
  int n0 = blockIdx.x * 32, k0 = blockIdx.y * 32;
  int isbf = *flag;
  #pragma unroll
  for (int r = 0; r < 4; ++r) {
    int k = k0 + ty + r * 8;
    int n = n0 + tx;
    float v = (n < ncols) ? load_elem(src, (size_t)k * ncols + n, isbf) : 0.f;
    tile[ty + r * 8][tx] = v;
  }
  __syncthreads();
  #pragma unroll
  for (int r = 0; r < 4; ++r) {
    int n = n0 + ty + r * 8;
    int k = k0 + tx;
    dst[(size_t)n * 1024 + k] = f2bf(tile[tx][ty + r * 8]);
  }
}

// ---------------- bf16-MFMA GEMM, 128x128 tile, K=1024, epilogue by MODE ----------------
// A: fp32 M x 1024 (converted to bf16 at staging). Bt: bf16 N x 1024 (row-major, K contig).
// MODE 1: o0 = x (n<1024), o1 = silu(z) (n>=1024)           [NT=2048]
// MODE 2: o0 = delta_raw (n<1024), o1 = B_ssm, o2 = C_ssm   [NT=1152, cols>=1056 discarded]
// MODE 3: o0 = softplus(v + b_dt[n])                        [NT=1024]
// MODE 4: o0 = v + x_in[m,n]                                [NT=1024]
template<int MODE>
__global__ __launch_bounds__(256, 2) void gemm_kernel(
    const float* __restrict__ A, const unsigned short* __restrict__ Bt,
    float* __restrict__ o0, float* __restrict__ o1, float* __restrict__ o2,
    const float* __restrict__ aux) {
  constexpr int LDK = 40;   // 32 bf16 + 8 pad: frag-read conflicts <= 2-way
  __shared__ __align__(16) unsigned short a_lds[128 * LDK];
  __shared__ __align__(16) unsigned short b_lds[128 * LDK];
  const int tid = threadIdx.x;
  const int m0 = blockIdx.x * 128, n0 = blockIdx.y * 128;
  const int wave = tid >> 6, lane = tid & 63;
  const int wr = (wave >> 1) * 64;   // wave's 64x64 sub-tile
  const int wc = (wave & 1) * 64;
  const int lrow = lane & 15, quad = lane >> 4;

  const int srow = tid >> 1;           // staging row 0..127
  const int koff = (tid & 1) << 4;     // 0 or 16
  const float* aptr = A + (size_t)(m0 + srow) * D_MODEL + koff;
  const unsigned short* bptr = Bt + (size_t)(n0 + srow) * D_MODEL + koff;
  unsigned short* a_st = &a_lds[srow * LDK + koff];
  unsigned short* b_st = &b_lds[srow * LDK + koff];
  const unsigned short* a_rd = &a_lds[(wr + lrow) * LDK + quad * 8];
  const unsigned short* b_rd = &b_lds[(wc + lrow) * LDK + quad * 8];

  f32x4 acc[4][4];
  #pragma unroll
  for (int i = 0; i < 4; ++i)
    #pragma unroll
    for (int jj = 0; jj < 4; ++jj)
      #pragma unroll
      for (int r = 0; r < 4; ++r) acc[i][jj][r] = 0.f;

  for (int kt = 0; kt < D_MODEL; kt += 32) {
    float4 a0 = *(const float4*)(aptr + 0);
    float4 a1 = *(const float4*)(aptr + 4);
    float4 a2 = *(const float4*)(aptr + 8);
    float4 a3 = *(const float4*)(aptr + 12);
    uint4 bv0 = *(const uint4*)(bptr + 0);
    uint4 bv1 = *(const uint4*)(bptr + 8);
    us8 p0, p1;
    p0[0] = f2bf(a0.x); p0[1] = f2bf(a0.y); p0[2] = f2bf(a0.z); p0[3] = f2bf(a0.w);
    p0[4] = f2bf(a1.x); p0[5] = f2bf(a1.y); p0[6] = f2bf(a1.z); p0[7] = f2bf(a1.w);
    p1[0] = f2bf(a2.x); p1[1] = f2bf(a2.y); p1[2] = f2bf(a2.z); p1[3] = f2bf(a2.w);
    p1[4] = f2bf(a3.x); p1[5] = f2bf(a3.y); p1[6] = f2bf(a3.z); p1[7] = f2bf(a3.w);
    *(us8*)a_st = p0;
    *(us8*)(a_st + 8) = p1;
    *(uint4*)b_st = bv0;
    *(uint4*)(b_st + 8) = bv1;
    __syncthreads();
    bf16x8 af[4], bfr[4];
    #pragma unroll
    for (int i = 0; i < 4; ++i) {
      af[i]  = *(const bf16x8*)(a_rd + i * 16 * LDK);
      bfr[i] = *(const bf16x8*)(b_rd + i * 16 * LDK);
    }
    #pragma unroll
    for (int i = 0; i < 4; ++i)
      #pragma unroll
      for (int jj = 0; jj < 4; ++jj)
        acc[i][jj] = __builtin_amdgcn_mfma_f32_16x16x32_bf16(af[i], bfr[jj], acc[i][jj], 0, 0, 0);
    __syncthreads();
    aptr += 32;
    bptr += 32;
  }

  // Epilogue. C/D layout: row = quad*4 + r, col = lane&15 (verified gfx950 mapping).
  #pragma unroll
  for (int i = 0; i < 4; ++i) {
    #pragma unroll
    for (int jj = 0; jj < 4; ++jj) {
      #pragma unroll
      for (int r = 0; r < 4; ++r) {
        int m = m0 + wr + i * 16 + quad * 4 + r;
        int n = n0 + wc + jj * 16 + lrow;
        float v = acc[i][jj][r];
        if (MODE == 1) {
          if (n < D_MODEL) {
            o0[(size_t)m * D_MODEL + n] = v;
          } else {
            float sig = 1.f / (1.f + expf(-v));
            o1[(size_t)m * D_MODEL + (n - D_MODEL)] = v * sig;   // silu(z)
          }
        } else if (MODE == 2) {
          if (n < D_MODEL)                 o0[(size_t)m * D_MODEL + n] = v;
          else if (n < D_MODEL + D_STATE)  o1[(size_t)m * D_STATE + (n - D_MODEL)] = v;
          else if (n < D_MODEL + 2*D_STATE)o2[(size_t)m * D_STATE + (n - D_MODEL - D_STATE)] = v;
          // n >= 1056: zero-padded columns, discard
        } else if (MODE == 3) {
          float t = v + aux[n];
          float sp = (t > 20.f) ? t : log1pf(expf(t));
          o0[(size_t)m * D_MODEL + n] = sp;
        } else {
          o0[(size_t)m * D_MODEL + n] = v + aux[(size_t)m * D_MODEL + n];
        }
      }
    }
  }
}

// ---------------- selective scan + fused g = (y + x*D)*silu(z) ----------------
// One thread per (b, d, n). Block = 16 d-channels x 16 states. Chunked over L
// in steps of 16 with register prefetch of the next chunk's globals.
__global__ __launch_bounds__(256) void scan_kernel(
    const float* __restrict__ delta, const float* __restrict__ xv_,
    const float* __restrict__ sv_, const float* __restrict__ Bs,
    const float* __restrict__ Cs, const float* __restrict__ alog,
    const float* __restrict__ Dpar, float* __restrict__ g) {
  __shared__ float d_s[256], x_s[256], z_s[256], b_s[256], c_s[256], y_s[256];
  const int tid = threadIdx.x;
  const int bid = blockIdx.x;           // 256 blocks
  const int b = bid >> 6;
  const int d0 = (bid & 63) << 4;
  const int dloc = tid >> 4;            // compute: which d (0..15)
  const int n = tid & 15;               // compute: which state
  const int d = d0 + dloc;

  const float Adn = -__expf(alog[(size_t)d * D_STATE + n]);
  const float Dpd = Dpar[d];
  float h = 0.f;

  const int il = tid >> 4;              // staging: l-offset within chunk
  const int j = tid & 15;               // staging: d-offset / state index
  size_t rowd = ((size_t)b * SEQ_L + il) * D_MODEL + d0 + j;
  size_t rown = ((size_t)b * SEQ_L + il) * D_STATE + j;

  float r_d = delta[rowd], r_x = xv_[rowd], r_z = sv_[rowd];
  float r_b = Bs[rown],    r_c = Cs[rown];

  for (int lc = 0; lc < SEQ_L / 16; ++lc) {
    d_s[tid] = r_d; x_s[tid] = r_x; z_s[tid] = r_z; b_s[tid] = r_b; c_s[tid] = r_c;
    size_t rowd_cur = rowd;
    __syncthreads();
    if (lc < SEQ_L / 16 - 1) {          // prefetch next chunk during compute
      rowd += (size_t)16 * D_MODEL;
      rown += (size_t)16 * D_STATE;
      r_d = delta[rowd]; r_x = xv_[rowd]; r_z = sv_[rowd];
      r_b = Bs[rown];    r_c = Cs[rown];
    }
    #pragma unroll
    for (int t = 0; t < 16; ++t) {
      float dl = d_s[t * 16 + dloc];
      float xx = x_s[t * 16 + dloc];
      float bb = b_s[t * 16 + n];
      float dA = __expf(dl * Adn);
      h = fmaf(dA, h, dl * xx * bb);
      float p = h * c_s[t * 16 + n];
      p += __shfl_xor(p, 1);
      p += __shfl_xor(p, 2);
      p += __shfl_xor(p, 4);
      p += __shfl_xor(p, 8);
      if (n == 0) y_s[t * 16 + dloc] = fmaf(xx, Dpd, p) * z_s[t * 16 + dloc];
    }
    __syncthreads();
    g[rowd_cur] = y_s[tid];
  }
}

// ---------------- LayerNorm over D=1024 per row ----------------
__global__ __launch_bounds__(256) void ln_kernel(const float* __restrict__ res,
    const float* __restrict__ lng, const float* __restrict__ lnb,
    void* __restrict__ out, const int* __restrict__ flag) {
  int row = blockIdx.x, tid = threadIdx.x;
  const float4* r4 = (const float4*)(res + (size_t)row * D_MODEL);
  float4 v = r4[tid];
  float s = v.x + v.y + v.z + v.w;
  float q = v.x * v.x + v.y * v.y + v.z * v.z + v.w * v.w;
  #pragma unroll
  for (int m = 1; m < 64; m <<= 1) { s += __shfl_xor(s, m); q += __shfl_xor(q, m); }
  __shared__ float ss[4], qs[4];
  int w = tid >> 6;
  if ((tid & 63) == 0) { ss[w] = s; qs[w] = q; }
  __syncthreads();
  s = ss[0] + ss[1] + ss[2] + ss[3];
  q = qs[0] + qs[1] + qs[2] + qs[3];
  float mu = s * (1.f / D_MODEL);
  float var = q * (1.f / D_MODEL) - mu * mu;
  float rstd = rsqrtf(var + 1e-5f);
  float4 gg = ((const float4*)lng)[tid];
  float4 bb = ((const float4*)lnb)[tid];
  float o0 = (v.x - mu) * rstd * gg.x + bb.x;
  float o1 = (v.y - mu) * rstd * gg.y + bb.y;
  float o2 = (v.z - mu) * rstd * gg.z + bb.z;
  float o3 = (v.w - mu) * rstd * gg.w + bb.w;
  if (*flag) {
    ushort4 pv;
    pv.x = f2bf(o0); pv.y = f2bf(o1); pv.z = f2bf(o2); pv.w = f2bf(o3);
    ((ushort4*)out)[(size_t)row * 256 + tid] = pv;
  } else {
    ((float4*)out)[(size_t)row * 256 + tid] = make_float4(o0, o1, o2, o3);
  }
}

extern "C" void kernel_launch(void* const* d_in, const int* in_sizes, int n_in,
                              void* d_out, int out_size, void* d_ws, size_t ws_size,
                              hipStream_t stream) {
  (void)in_sizes; (void)n_in; (void)out_size; (void)ws_size;
  const void* x_in  = d_in[0];
  const void* W_in  = d_in[1];
  const void* W_x   = d_in[2];
  const void* W_dt  = d_in[3];
  const void* b_dt  = d_in[4];
  const void* A_log = d_in[5];
  const void* D_par = d_in[6];
  const void* W_out = d_in[7];
  const void* ln_g  = d_in[8];
  const void* ln_b  = d_in[9];

  char* ws = (char*)d_ws;
  size_t off = 0;
  auto alloc = [&](size_t bytes) -> void* {
    void* p = ws + off;
    off += (bytes + 255) & ~(size_t)255;
    return p;
  };
  int* flag             = (int*)alloc(16);
  float* x_in_f         = (float*)alloc((size_t)M_ROWS * D_MODEL * 4);
  float* bdt_f          = (float*)alloc(1024 * 4);
  float* alog_f         = (float*)alloc(16384 * 4);
  float* dp_f           = (float*)alloc(1024 * 4);
  float* lng_f          = (float*)alloc(1024 * 4);
  float* lnb_f          = (float*)alloc(1024 * 4);
  unsigned short* wt_in  = (unsigned short*)alloc((size_t)2048 * 1024 * 2);
  unsigned short* wt_x   = (unsigned short*)alloc((size_t)1152 * 1024 * 2);
  unsigned short* wt_dt  = (unsigned short*)alloc((size_t)1024 * 1024 * 2);
  unsigned short* wt_out = (unsigned short*)alloc((size_t)1024 * 1024 * 2);
  float* x_f            = (float*)alloc((size_t)M_ROWS * D_MODEL * 4);
  float* s_f            = (float*)alloc((size_t)M_ROWS * D_MODEL * 4);  // silu(z)
  float* draw_f         = (float*)alloc((size_t)M_ROWS * D_MODEL * 4);
  float* bssm_f         = (float*)alloc((size_t)M_ROWS * D_STATE * 4);
  float* cssm_f         = (float*)alloc((size_t)M_ROWS * D_STATE * 4);
  float* delta_f        = (float*)alloc((size_t)M_ROWS * D_MODEL * 4);
  float* g_f    = draw_f;  // alias: draw consumed by GEMM3 before scan writes g
  float* out4_f = s_f;     // alias: silu(z) consumed by scan before GEMM4 writes

  detect_kernel<<<1, 256, 0, stream>>>((const unsigned short*)x_in, flag);
  convert_x_kernel<<<2048, 256, 0, stream>>>(x_in, x_in_f, flag);
  convert_smalls_kernel<<<80, 256, 0, stream>>>(b_dt, A_log, D_par, ln_g, ln_b,
                                                bdt_f, alog_f, dp_f, lng_f, lnb_f, flag);
  dim3 tb(32, 8);
  transpose_w_kernel<<<dim3(64, 32), tb, 0, stream>>>(W_in,  wt_in,  2048, flag);
  transpose_w_kernel<<<dim3(36, 32), tb, 0, stream>>>(W_x,   wt_x,   1056, flag);
  transpose_w_kernel<<<dim3(32, 32), tb, 0, stream>>>(W_dt,  wt_dt,  1024, flag);
  transpose_w_kernel<<<dim3(32, 32), tb, 0, stream>>>(W_out, wt_out, 1024, flag);

  gemm_kernel<1><<<dim3(32, 16), 256, 0, stream>>>(x_in_f, wt_in, x_f, s_f, nullptr, nullptr);
  gemm_kernel<2><<<dim3(32, 9),  256, 0, stream>>>(x_f, wt_x, draw_f, bssm_f, cssm_f, nullptr);
  gemm_kernel<3><<<dim3(32, 8),  256, 0, stream>>>(draw_f, wt_dt, delta_f, nullptr, nullptr, bdt_f);
  scan_kernel<<<256, 256, 0, stream>>>(delta_f, x_f, s_f, bssm_f, cssm_f, alog_f, dp_f, g_f);
  gemm_kernel<4><<<dim3(32, 8),  256, 0, stream>>>(g_f, wt_out, out4_f, nullptr, nullptr, x_in_f);
  ln_kernel<<<4096, 256, 0, stream>>>(out4_f, lng_f, lnb_f, d_out, flag);
}

// Round 2
// 540.339 us; speedup vs baseline: 1.0005x; 1.0005x over previous
//
#include <hip/hip_runtime.h>

#define D_MODEL 1024
#define D_STATE 16
#define M_ROWS  4096   // B*L
#define SEQ_L   1024
#define NSEG    32
#define LSEG    32     // SEQ_L / NSEG

typedef __bf16 bf16x8 __attribute__((ext_vector_type(8)));
typedef float  f32x4  __attribute__((ext_vector_type(4)));

__device__ __forceinline__ unsigned short f2bf(float f) {
  unsigned int u = __builtin_bit_cast(unsigned int, f);
  u += 0x7fffu + ((u >> 16) & 1u);           // RNE
  return (unsigned short)(u >> 16);
}
__device__ __forceinline__ float bf2f(unsigned short b) {
  unsigned int u = ((unsigned int)b) << 16;
  return __builtin_bit_cast(float, u);
}
__device__ __forceinline__ float load_elem(const void* p, size_t i, int isbf) {
  if (isbf) return bf2f(((const unsigned short*)p)[i]);
  return ((const float*)p)[i];
}

// async global->LDS, 16B per lane. LDS dest = (wave-uniform base) + lane*16.
// CK-style addrspace casts: generic->AS1 is bit-identical; generic LDS ptr's
// low 32 bits are the AS3 offset (shared aperture is in the high word).
__device__ __forceinline__ void gload16(const void* g, void* l) {
  typedef const __attribute__((address_space(1))) unsigned int GU;
  typedef __attribute__((address_space(3))) unsigned int LU;
  __builtin_amdgcn_global_load_lds((GU*)(unsigned long long)g,
                                   (LU*)(unsigned int)(unsigned long long)l,
                                   16, 0, 0);
}

// ---------------- dtype detection (unchanged, worked in R1) ----------------
__global__ void detect_kernel(const unsigned short* __restrict__ x, int* __restrict__ flag) {
  __shared__ int cnt;
  if (threadIdx.x == 0) cnt = 0;
  __syncthreads();
  unsigned int v = x[2 * threadIdx.x];
  unsigned int e = (v >> 7) & 0xFFu;
  int ok = (e >= 100u && e <= 135u) ? 1 : 0;
  atomicAdd(&cnt, ok);
  __syncthreads();
  if (threadIdx.x == 0) *flag = (cnt >= 128) ? 1 : 0;
}

// ---------------- x_in -> fp32 (residual/aux) + bf16 (GEMM1 A) ----------------
__global__ void convert_x_kernel(const void* __restrict__ src, float* __restrict__ dstf,
                                 unsigned short* __restrict__ dstb,
                                 const int* __restrict__ flag) {
  int c = blockIdx.x * blockDim.x + threadIdx.x;  // chunk of 8 elems
  int isbf = *flag;
  float o[8];
  if (isbf) {
    uint4 v = ((const uint4*)src)[c];
    o[0] = bf2f((unsigned short)(v.x & 0xffffu)); o[1] = bf2f((unsigned short)(v.x >> 16));
    o[2] = bf2f((unsigned short)(v.y & 0xffffu)); o[3] = bf2f((unsigned short)(v.y >> 16));
    o[4] = bf2f((unsigned short)(v.z & 0xffffu)); o[5] = bf2f((unsigned short)(v.z >> 16));
    o[6] = bf2f((unsigned short)(v.w & 0xffffu)); o[7] = bf2f((unsigned short)(v.w >> 16));
    ((uint4*)dstb)[c] = v;                         // already bf16: raw copy
  } else {
    float4 a = ((const float4*)src)[2 * c];
    float4 b = ((const float4*)src)[2 * c + 1];
    o[0]=a.x; o[1]=a.y; o[2]=a.z; o[3]=a.w; o[4]=b.x; o[5]=b.y; o[6]=b.z; o[7]=b.w;
    uint4 p;
    p.x = (unsigned int)f2bf(o[0]) | ((unsigned int)f2bf(o[1]) << 16);
    p.y = (unsigned int)f2bf(o[2]) | ((unsigned int)f2bf(o[3]) << 16);
    p.z = (unsigned int)f2bf(o[4]) | ((unsigned int)f2bf(o[5]) << 16);
    p.w = (unsigned int)f2bf(o[6]) | ((unsigned int)f2bf(o[7]) << 16);
    ((uint4*)dstb)[c] = p;
  }
  float4* d = (float4*)dstf;
  d[2*c]   = make_float4(o[0], o[1], o[2], o[3]);
  d[2*c+1] = make_float4(o[4], o[5], o[6], o[7]);
}

// ---------------- small vectors; A_log -> A2 = -exp(A_log)*log2(e) ----------------
__global__ void convert_smalls_kernel(const void* b_dt, const void* A_log, const void* Dp,
                                      const void* ln_g, const void* ln_b,
                                      float* o_bdt, float* o_a2, float* o_dp,
                                      float* o_lng, float* o_lnb,
                                      const int* __restrict__ flag) {
  int g = blockIdx.x * blockDim.x + threadIdx.x;  // 0..20479
  int isbf = *flag;
  if (g < 1024)              o_bdt[g]          = load_elem(b_dt, g, isbf);
  else if (g < 17408) {
    float v = load_elem(A_log, g - 1024, isbf);
    o_a2[g - 1024] = -expf(v) * 1.4426950408889634f;
  }
  else if (g < 18432)        o_dp[g - 17408]   = load_elem(Dp, g - 17408, isbf);
  else if (g < 19456)        o_lng[g - 18432]  = load_elem(ln_g, g - 18432, isbf);
  else                       o_lnb[g - 19456]  = load_elem(ln_b, g - 19456, isbf);
}

// ---------------- weight transpose: (K=1024 x ncols) -> bf16 (nrows x 1024) ----------------
__global__ void transpose_w_kernel(const void* __restrict__ src, unsigned short* __restrict__ dst,
                                   int ncols, const int* __restrict__ flag) {
  __shared__ float tile[32][33];
  int tx = threadIdx.x, ty = threadIdx.y;   // 32 x 8
  int n0 = blockIdx.x * 32, k0 = blockIdx.y * 32;
  int isbf = *flag;
  #pragma unroll
  for (int r = 0; r < 4; ++r) {
    int k = k0 + ty + r * 8;
    int n = n0 + tx;
    float v = (n < ncols) ? load_elem(src, (size_t)k * ncols + n, isbf) : 0.f;
    tile[ty + r * 8][tx] = v;
  }
  __syncthreads();
  #pragma unroll
  for (int r = 0; r < 4; ++r) {
    int n = n0 + ty + r * 8;
    int k = k0 + tx;
    dst[(size_t)n * 1024 + k] = f2bf(tile[tx][ty + r * 8]);
  }
}

// ---------------- bf16 MFMA GEMM, 128x128 tile, global_load_lds staging ----------------
// A: bf16 M x 1024. Bt: bf16 N x 1024 (K contiguous). LDS rows = 32 bf16 (64B),
// stored as 4x16B chunks, chunk slot s holds K-chunk s ^ ((row>>1)&3) (XOR swizzle
// -> frag ds_read_b128 is 2-way bank-aliased = free; staging absorbs swizzle in the
// per-lane GLOBAL address since LDS dest is fixed base+lane*16).
// MODE 1: o0=x (bf16), o1=silu(z) (bf16)         [N=2048]
// MODE 2: o0=delta_raw (bf16), o1=B_ssm (f32), o2=C_ssm (f32)  [N=1152, >=1056 discard]
// MODE 3: o0=softplus(v + aux[n]) (bf16)         [N=1024]
// MODE 4: o0=v + aux[m,n] (f32)                  [N=1024]
template<int MODE>
__global__ __launch_bounds__(256, 2) void gemm_bf(
    const unsigned short* __restrict__ A, const unsigned short* __restrict__ Bt,
    void* __restrict__ o0, void* __restrict__ o1, float* __restrict__ o2f,
    const float* __restrict__ aux) {
  __shared__ __align__(16) unsigned short a_lds[128 * 32];
  __shared__ __align__(16) unsigned short b_lds[128 * 32];
  const int tid = threadIdx.x;
  const int m0 = blockIdx.x * 128, n0 = blockIdx.y * 128;
  const int wave = tid >> 6, lane = tid & 63;
  const int wr = (wave >> 1) * 64, wc = (wave & 1) * 64;
  const int lrow = lane & 15, quad = lane >> 4;

  // staging: wave covers rows [wave*32, wave*32+32); 2 instrs of 16 rows each.
  // lane l -> localrow l>>2, slot l&3; global chunk = (l&3) ^ ((l>>3)&3).
  const int srow = wave * 32 + (lane >> 2);
  const int sc = (lane & 3) ^ ((lane >> 3) & 3);
  const unsigned short* ga0 = A  + (size_t)(m0 + srow) * 1024 + sc * 8;
  const unsigned short* ga1 = A  + (size_t)(m0 + srow + 16) * 1024 + sc * 8;
  const unsigned short* gb0 = Bt + (size_t)(n0 + srow) * 1024 + sc * 8;
  const unsigned short* gb1 = Bt + (size_t)(n0 + srow + 16) * 1024 + sc * 8;
  unsigned short* la0 = a_lds + (wave * 32) * 32;
  unsigned short* la1 = a_lds + (wave * 32 + 16) * 32;
  unsigned short* lb0 = b_lds + (wave * 32) * 32;
  unsigned short* lb1 = b_lds + (wave * 32 + 16) * 32;

  // frag reads: row = (wr|wc) + i*16 + lrow; chunk = quad ^ ((lrow>>1)&3)
  // ((row>>1)&3 == (lrow>>1)&3 since the rest is a multiple of 16)
  const int q2 = quad ^ ((lrow >> 1) & 3);
  const unsigned short* a_rd = a_lds + (wr + lrow) * 32 + q2 * 8;
  const unsigned short* b_rd = b_lds + (wc + lrow) * 32 + q2 * 8;

  f32x4 acc[4][4];
  #pragma unroll
  for (int i = 0; i < 4; ++i)
    #pragma unroll
    for (int jj = 0; jj < 4; ++jj)
      #pragma unroll
      for (int r = 0; r < 4; ++r) acc[i][jj][r] = 0.f;

  for (int kt = 0; kt < D_MODEL; kt += 32) {
    gload16(ga0, la0); gload16(ga1, la1);
    gload16(gb0, lb0); gload16(gb1, lb1);
    ga0 += 32; ga1 += 32; gb0 += 32; gb1 += 32;
    __syncthreads();            // drains vmcnt -> staged data visible
    bf16x8 af[4], bfr[4];
    #pragma unroll
    for (int i = 0; i < 4; ++i) {
      af[i]  = *(const bf16x8*)(a_rd + i * 16 * 32);
      bfr[i] = *(const bf16x8*)(b_rd + i * 16 * 32);
    }
    #pragma unroll
    for (int i = 0; i < 4; ++i)
      #pragma unroll
      for (int jj = 0; jj < 4; ++jj)
        acc[i][jj] = __builtin_amdgcn_mfma_f32_16x16x32_bf16(af[i], bfr[jj], acc[i][jj], 0, 0, 0);
    __syncthreads();            // reads done before next stage overwrites
  }

  // C/D layout: row = quad*4 + r, col = lane&15.
  #pragma unroll
  for (int i = 0; i < 4; ++i) {
    #pragma unroll
    for (int jj = 0; jj < 4; ++jj) {
      #pragma unroll
      for (int r = 0; r < 4; ++r) {
        int m = m0 + wr + i * 16 + quad * 4 + r;
        int n = n0 + wc + jj * 16 + lrow;
        float v = acc[i][jj][r];
        if (MODE == 1) {
          if (n < D_MODEL) {
            ((unsigned short*)o0)[(size_t)m * D_MODEL + n] = f2bf(v);
          } else {
            float sig = 1.f / (1.f + expf(-v));
            ((unsigned short*)o1)[(size_t)m * D_MODEL + (n - D_MODEL)] = f2bf(v * sig);
          }
        } else if (MODE == 2) {
          if (n < D_MODEL)                  ((unsigned short*)o0)[(size_t)m * D_MODEL + n] = f2bf(v);
          else if (n < D_MODEL + D_STATE)   ((float*)o1)[(size_t)m * D_STATE + (n - D_MODEL)] = v;
          else if (n < D_MODEL + 2*D_STATE) o2f[(size_t)m * D_STATE + (n - D_MODEL - D_STATE)] = v;
        } else if (MODE == 3) {
          float t = v + aux[n];
          float sp = (t > 20.f) ? t : log1pf(expf(t));
          ((unsigned short*)o0)[(size_t)m * D_MODEL + n] = f2bf(sp);
        } else {
          ((float*)o0)[(size_t)m * D_MODEL + n] = v + aux[(size_t)m * D_MODEL + n];
        }
      }
    }
  }
}

// ---------------- chunked parallel scan ----------------
// Channel = (b,d); thread holds h[0..15] in registers. Segments of LSEG=32 steps.
// PHASE 0: from h=0, produce H (final h) + sum(delta) per segment.
// PHASE 1: from h=hinit, produce g = (y + x*D)*silu(z), bf16.
template<int PHASE>
__global__ __launch_bounds__(256) void scan_phase(
    const unsigned short* __restrict__ dl_bf, const unsigned short* __restrict__ x_bf,
    const unsigned short* __restrict__ z_bf, const float* __restrict__ Bs,
    const float* __restrict__ Cs, const float* __restrict__ A2g,
    const float* __restrict__ Dpar, const float* __restrict__ hinit,
    float* __restrict__ Hout, float* __restrict__ sdout,
    unsigned short* __restrict__ g) {
  __shared__ float4 bsh[LSEG][4];
  __shared__ float4 csh[LSEG][4];
  const int tid = threadIdx.x;
  const int bid = blockIdx.x;                 // seg(32) x b(4) x dchunk(4) = 512
  const int seg = bid >> 4;
  const int b = (bid >> 2) & 3;
  const int dc = bid & 3;
  const int d = dc * 256 + tid;
  const int t0 = seg * LSEG;
  const int bd = b * D_MODEL + d;

  if (tid < 128) {                            // stage B (and C) segment rows
    int r = tid >> 2, q = tid & 3;
    size_t src = ((size_t)b * SEQ_L + t0 + r) * 4 + q;
    bsh[r][q] = ((const float4*)Bs)[src];
    if (PHASE == 1) csh[r][q] = ((const float4*)Cs)[src];
  }

  float A2r[16];
  {
    const float4* a4 = (const float4*)(A2g + (size_t)d * 16);
    #pragma unroll
    for (int q = 0; q < 4; ++q) {
      float4 v = a4[q];
      A2r[4*q] = v.x; A2r[4*q+1] = v.y; A2r[4*q+2] = v.z; A2r[4*q+3] = v.w;
    }
  }
  float h[16];
  if (PHASE == 1) {
    const float4* h4 = (const float4*)(hinit + (((size_t)seg * 4096) + bd) * 16);
    #pragma unroll
    for (int q = 0; q < 4; ++q) {
      float4 v = h4[q];
      h[4*q] = v.x; h[4*q+1] = v.y; h[4*q+2] = v.z; h[4*q+3] = v.w;
    }
  } else {
    #pragma unroll
    for (int n = 0; n < 16; ++n) h[n] = 0.f;
  }
  const float Dpd = (PHASE == 1) ? Dpar[d] : 0.f;
  float sd = 0.f;
  const size_t base = ((size_t)b * SEQ_L + t0) * D_MODEL + d;
  __syncthreads();

  unsigned short dreg[2][8], xreg[2][8], zreg[2][8];
  #pragma unroll
  for (int t = 0; t < 8; ++t) {
    size_t o = base + (size_t)t * D_MODEL;
    dreg[0][t] = dl_bf[o]; xreg[0][t] = x_bf[o];
    if (PHASE == 1) zreg[0][t] = z_bf[o];
  }
  #pragma unroll
  for (int c = 0; c < LSEG / 8; ++c) {
    const int cur = c & 1, nxt = cur ^ 1;
    if (c < LSEG / 8 - 1) {                   // prefetch next 8 steps
      #pragma unroll
      for (int t = 0; t < 8; ++t) {
        size_t o = base + (size_t)((c + 1) * 8 + t) * D_MODEL;
        dreg[nxt][t] = dl_bf[o]; xreg[nxt][t] = x_bf[o];
        if (PHASE == 1) zreg[nxt][t] = z_bf[o];
      }
    }
    #pragma unroll
    for (int t = 0; t < 8; ++t) {
      const int tt = c * 8 + t;
      float dl = bf2f(dreg[cur][t]);
      float xx = bf2f(xreg[cur][t]);
      float dx = dl * xx;
      sd += dl;
      float4 b0 = bsh[tt][0], b1 = bsh[tt][1], b2 = bsh[tt][2], b3 = bsh[tt][3];
      float bb[16] = {b0.x,b0.y,b0.z,b0.w, b1.x,b1.y,b1.z,b1.w,
                      b2.x,b2.y,b2.z,b2.w, b3.x,b3.y,b3.z,b3.w};
      if (PHASE == 0) {
        #pragma unroll
        for (int n = 0; n < 16; ++n) {
          float dA = exp2f(dl * A2r[n]);
          h[n] = fmaf(dA, h[n], dx * bb[n]);
        }
      } else {
        float4 c0 = csh[tt][0], c1 = csh[tt][1], c2 = csh[tt][2], c3 = csh[tt][3];
        float cc[16] = {c0.x,c0.y,c0.z,c0.w, c1.x,c1.y,c1.z,c1.w,
                        c2.x,c2.y,c2.z,c2.w, c3.x,c3.y,c3.z,c3.w};
        float y = 0.f;
        #pragma unroll
        for (int n = 0; n < 16; ++n) {
          float dA = exp2f(dl * A2r[n]);
          h[n] = fmaf(dA, h[n], dx * bb[n]);
          y = fmaf(h[n], cc[n], y);
        }
        float zz = bf2f(zreg[cur][t]);
        g[base + (size_t)tt * D_MODEL] = f2bf(fmaf(xx, Dpd, y) * zz);
      }
    }
  }
  if (PHASE == 0) {
    float4* ho = (float4*)(Hout + (((size_t)seg * 4096) + bd) * 16);
    #pragma unroll
    for (int q = 0; q < 4; ++q)
      ho[q] = make_float4(h[4*q], h[4*q+1], h[4*q+2], h[4*q+3]);
    sdout[(size_t)seg * 4096 + bd] = sd;
  }
}

// segment-level scan: h_init(s) = P(s-1)*h_init(s-1) + H(s-1), P = exp2(A2*sumdelta)
__global__ __launch_bounds__(256) void scan_phaseB(
    const float* __restrict__ H, const float* __restrict__ sdelta,
    const float* __restrict__ A2g, float* __restrict__ hinit) {
  int gidx = blockIdx.x * 256 + threadIdx.x;   // 65536 = bd(4096) x n(16)
  int bd = gidx >> 4, n = gidx & 15;
  float A2 = A2g[(size_t)(bd & (D_MODEL - 1)) * 16 + n];
  float hp = 0.f;
  #pragma unroll
  for (int s = 0; s < NSEG; ++s) {
    size_t idx = ((size_t)s * 4096 + bd) * 16 + n;
    hinit[idx] = hp;
    float P = exp2f(A2 * sdelta[(size_t)s * 4096 + bd]);
    hp = fmaf(P, hp, H[idx]);
  }
}

// ---------------- LayerNorm over D=1024 per row ----------------
__global__ __launch_bounds__(256) void ln_kernel(const float* __restrict__ res,
    const float* __restrict__ lng, const float* __restrict__ lnb,
    void* __restrict__ out, const int* __restrict__ flag) {
  int row = blockIdx.x, tid = threadIdx.x;
  const float4* r4 = (const float4*)(res + (size_t)row * D_MODEL);
  float4 v = r4[tid];
  float s = v.x + v.y + v.z + v.w;
  float q = v.x * v.x + v.y * v.y + v.z * v.z + v.w * v.w;
  #pragma unroll
  for (int m = 1; m < 64; m <<= 1) { s += __shfl_xor(s, m); q += __shfl_xor(q, m); }
  __shared__ float ss[4], qs[4];
  int w = tid >> 6;
  if ((tid & 63) == 0) { ss[w] = s; qs[w] = q; }
  __syncthreads();
  s = ss[0] + ss[1] + ss[2] + ss[3];
  q = qs[0] + qs[1] + qs[2] + qs[3];
  float mu = s * (1.f / D_MODEL);
  float var = q * (1.f / D_MODEL) - mu * mu;
  float rstd = rsqrtf(var + 1e-5f);
  float4 gg = ((const float4*)lng)[tid];
  float4 bb = ((const float4*)lnb)[tid];
  float o0 = (v.x - mu) * rstd * gg.x + bb.x;
  float o1 = (v.y - mu) * rstd * gg.y + bb.y;
  float o2 = (v.z - mu) * rstd * gg.z + bb.z;
  float o3 = (v.w - mu) * rstd * gg.w + bb.w;
  if (*flag) {
    ushort4 pv;
    pv.x = f2bf(o0); pv.y = f2bf(o1); pv.z = f2bf(o2); pv.w = f2bf(o3);
    ((ushort4*)out)[(size_t)row * 256 + tid] = pv;
  } else {
    ((float4*)out)[(size_t)row * 256 + tid] = make_float4(o0, o1, o2, o3);
  }
}

extern "C" void kernel_launch(void* const* d_in, const int* in_sizes, int n_in,
                              void* d_out, int out_size, void* d_ws, size_t ws_size,
                              hipStream_t stream) {
  (void)in_sizes; (void)n_in; (void)out_size; (void)ws_size;
  const void* x_in  = d_in[0];
  const void* W_in  = d_in[1];
  const void* W_x   = d_in[2];
  const void* W_dt  = d_in[3];
  const void* b_dt  = d_in[4];
  const void* A_log = d_in[5];
  const void* D_par = d_in[6];
  const void* W_out = d_in[7];
  const void* ln_g  = d_in[8];
  const void* ln_b  = d_in[9];

  char* ws = (char*)d_ws;
  size_t off = 0;
  auto alloc = [&](size_t bytes) -> void* {
    void* p = ws + off;
    off += (bytes + 255) & ~(size_t)255;
    return p;
  };
  int* flag              = (int*)alloc(16);
  float* x_in_f          = (float*)alloc((size_t)M_ROWS * D_MODEL * 4);
  unsigned short* x_in_b = (unsigned short*)alloc((size_t)M_ROWS * D_MODEL * 2);
  float* bdt_f           = (float*)alloc(1024 * 4);
  float* a2_f            = (float*)alloc(16384 * 4);
  float* dp_f            = (float*)alloc(1024 * 4);
  float* lng_f           = (float*)alloc(1024 * 4);
  float* lnb_f           = (float*)alloc(1024 * 4);
  unsigned short* wt_in  = (unsigned short*)alloc((size_t)2048 * 1024 * 2);
  unsigned short* wt_x   = (unsigned short*)alloc((size_t)1152 * 1024 * 2);
  unsigned short* wt_dt  = (unsigned short*)alloc((size_t)1024 * 1024 * 2);
  unsigned short* wt_out = (unsigned short*)alloc((size_t)1024 * 1024 * 2);
  unsigned short* x_bf   = (unsigned short*)alloc((size_t)M_ROWS * D_MODEL * 2);
  unsigned short* s_bf   = (unsigned short*)alloc((size_t)M_ROWS * D_MODEL * 2);  // silu(z)
  unsigned short* draw_bf= (unsigned short*)alloc((size_t)M_ROWS * D_MODEL * 2);
  unsigned short* delta_bf=(unsigned short*)alloc((size_t)M_ROWS * D_MODEL * 2);
  float* bssm_f          = (float*)alloc((size_t)M_ROWS * D_STATE * 4);
  float* cssm_f          = (float*)alloc((size_t)M_ROWS * D_STATE * 4);
  float* H_f             = (float*)alloc((size_t)NSEG * 4096 * 16 * 4);
  float* hinit_f         = (float*)alloc((size_t)NSEG * 4096 * 16 * 4);
  float* sdelta_f        = (float*)alloc((size_t)NSEG * 4096 * 4);
  unsigned short* g_bf = draw_bf;   // alias: draw consumed by GEMM3 before scanC writes g
  float* res_f = (float*)x_bf;      // alias: x_bf+s_bf (16MB contiguous) consumed by scanC
                                    // before GEMM4 writes res

  detect_kernel<<<1, 256, 0, stream>>>((const unsigned short*)x_in, flag);
  convert_x_kernel<<<2048, 256, 0, stream>>>(x_in, x_in_f, x_in_b, flag);
  convert_smalls_kernel<<<80, 256, 0, stream>>>(b_dt, A_log, D_par, ln_g, ln_b,
                                                bdt_f, a2_f, dp_f, lng_f, lnb_f, flag);
  dim3 tb(32, 8);
  transpose_w_kernel<<<dim3(64, 32), tb, 0, stream>>>(W_in,  wt_in,  2048, flag);
  transpose_w_kernel<<<dim3(36, 32), tb, 0, stream>>>(W_x,   wt_x,   1056, flag);
  transpose_w_kernel<<<dim3(32, 32), tb, 0, stream>>>(W_dt,  wt_dt,  1024, flag);
  transpose_w_kernel<<<dim3(32, 32), tb, 0, stream>>>(W_out, wt_out, 1024, flag);

  gemm_bf<1><<<dim3(32, 16), 256, 0, stream>>>(x_in_b, wt_in, x_bf, s_bf, nullptr, nullptr);
  gemm_bf<2><<<dim3(32, 9),  256, 0, stream>>>(x_bf, wt_x, draw_bf, bssm_f, cssm_f, nullptr);
  gemm_bf<3><<<dim3(32, 8),  256, 0, stream>>>(draw_bf, wt_dt, delta_bf, nullptr, nullptr, bdt_f);

  scan_phase<0><<<512, 256, 0, stream>>>(delta_bf, x_bf, nullptr, bssm_f, nullptr,
                                         a2_f, nullptr, nullptr, H_f, sdelta_f, nullptr);
  scan_phaseB<<<256, 256, 0, stream>>>(H_f, sdelta_f, a2_f, hinit_f);
  scan_phase<1><<<512, 256, 0, stream>>>(delta_bf, x_bf, s_bf, bssm_f, cssm_f,
                                         a2_f, dp_f, hinit_f, nullptr, nullptr, g_bf);

  gemm_bf<4><<<dim3(32, 8),  256, 0, stream>>>(g_bf, wt_out, res_f, nullptr, nullptr, x_in_f);
  ln_kernel<<<4096, 256, 0, stream>>>(res_f, lng_f, lnb_f, d_out, flag);
}

// Round 3
// 289.066 us; speedup vs baseline: 1.8702x; 1.8693x over previous
//
#include <hip/hip_runtime.h>

#define D_MODEL 1024
#define D_STATE 16
#define M_ROWS  4096   // B*L
#define SEQ_L   1024
#define NSEG    32
#define LSEG    32     // SEQ_L / NSEG

typedef __bf16 bf16x8 __attribute__((ext_vector_type(8)));
typedef float  f32x4  __attribute__((ext_vector_type(4)));

__device__ __forceinline__ unsigned short f2bf(float f) {
  unsigned int u = __builtin_bit_cast(unsigned int, f);
  u += 0x7fffu + ((u >> 16) & 1u);           // RNE
  return (unsigned short)(u >> 16);
}
__device__ __forceinline__ float bf2f(unsigned short b) {
  unsigned int u = ((unsigned int)b) << 16;
  return __builtin_bit_cast(float, u);
}
__device__ __forceinline__ float load_elem(const void* p, size_t i, int isbf) {
  if (isbf) return bf2f(((const unsigned short*)p)[i]);
  return ((const float*)p)[i];
}

// async global->LDS, 16B per lane. LDS dest = (wave-uniform base) + lane*16.
__device__ __forceinline__ void gload16(const void* g, void* l) {
  typedef const __attribute__((address_space(1))) unsigned int GU;
  typedef __attribute__((address_space(3))) unsigned int LU;
  __builtin_amdgcn_global_load_lds((GU*)(unsigned long long)g,
                                   (LU*)(unsigned int)(unsigned long long)l,
                                   16, 0, 0);
}

// ---------------- dtype detection ----------------
__global__ void detect_kernel(const unsigned short* __restrict__ x, int* __restrict__ flag) {
  __shared__ int cnt;
  if (threadIdx.x == 0) cnt = 0;
  __syncthreads();
  unsigned int v = x[2 * threadIdx.x];
  unsigned int e = (v >> 7) & 0xFFu;
  int ok = (e >= 100u && e <= 135u) ? 1 : 0;
  atomicAdd(&cnt, ok);
  __syncthreads();
  if (threadIdx.x == 0) *flag = (cnt >= 128) ? 1 : 0;
}

// ---------------- x_in -> fp32 (residual/aux) + bf16 (GEMM1 A) ----------------
__global__ void convert_x_kernel(const void* __restrict__ src, float* __restrict__ dstf,
                                 unsigned short* __restrict__ dstb,
                                 const int* __restrict__ flag) {
  int c = blockIdx.x * blockDim.x + threadIdx.x;  // chunk of 8 elems
  int isbf = *flag;
  float o[8];
  if (isbf) {
    uint4 v = ((const uint4*)src)[c];
    o[0] = bf2f((unsigned short)(v.x & 0xffffu)); o[1] = bf2f((unsigned short)(v.x >> 16));
    o[2] = bf2f((unsigned short)(v.y & 0xffffu)); o[3] = bf2f((unsigned short)(v.y >> 16));
    o[4] = bf2f((unsigned short)(v.z & 0xffffu)); o[5] = bf2f((unsigned short)(v.z >> 16));
    o[6] = bf2f((unsigned short)(v.w & 0xffffu)); o[7] = bf2f((unsigned short)(v.w >> 16));
    ((uint4*)dstb)[c] = v;                         // already bf16: raw copy
  } else {
    float4 a = ((const float4*)src)[2 * c];
    float4 b = ((const float4*)src)[2 * c + 1];
    o[0]=a.x; o[1]=a.y; o[2]=a.z; o[3]=a.w; o[4]=b.x; o[5]=b.y; o[6]=b.z; o[7]=b.w;
    uint4 p;
    p.x = (unsigned int)f2bf(o[0]) | ((unsigned int)f2bf(o[1]) << 16);
    p.y = (unsigned int)f2bf(o[2]) | ((unsigned int)f2bf(o[3]) << 16);
    p.z = (unsigned int)f2bf(o[4]) | ((unsigned int)f2bf(o[5]) << 16);
    p.w = (unsigned int)f2bf(o[6]) | ((unsigned int)f2bf(o[7]) << 16);
    ((uint4*)dstb)[c] = p;
  }
  float4* d = (float4*)dstf;
  d[2*c]   = make_float4(o[0], o[1], o[2], o[3]);
  d[2*c+1] = make_float4(o[4], o[5], o[6], o[7]);
}

// ---------------- small vectors; A_log -> A2 = -exp(A_log)*log2(e) ----------------
__global__ void convert_smalls_kernel(const void* b_dt, const void* A_log, const void* Dp,
                                      const void* ln_g, const void* ln_b,
                                      float* o_bdt, float* o_a2, float* o_dp,
                                      float* o_lng, float* o_lnb,
                                      const int* __restrict__ flag) {
  int g = blockIdx.x * blockDim.x + threadIdx.x;  // 0..20479
  int isbf = *flag;
  if (g < 1024)              o_bdt[g]          = load_elem(b_dt, g, isbf);
  else if (g < 17408) {
    float v = load_elem(A_log, g - 1024, isbf);
    o_a2[g - 1024] = -expf(v) * 1.4426950408889634f;
  }
  else if (g < 18432)        o_dp[g - 17408]   = load_elem(Dp, g - 17408, isbf);
  else if (g < 19456)        o_lng[g - 18432]  = load_elem(ln_g, g - 18432, isbf);
  else                       o_lnb[g - 19456]  = load_elem(ln_b, g - 19456, isbf);
}

// ---------------- weight transpose: (K=1024 x ncols) -> bf16 (nrows x 1024) ----------------
__global__ void transpose_w_kernel(const void* __restrict__ src, unsigned short* __restrict__ dst,
                                   int ncols, const int* __restrict__ flag) {
  __shared__ float tile[32][33];
  int tx = threadIdx.x, ty = threadIdx.y;   // 32 x 8
  int n0 = blockIdx.x * 32, k0 = blockIdx.y * 32;
  int isbf = *flag;
  #pragma unroll
  for (int r = 0; r < 4; ++r) {
    int k = k0 + ty + r * 8;
    int n = n0 + tx;
    float v = (n < ncols) ? load_elem(src, (size_t)k * ncols + n, isbf) : 0.f;
    tile[ty + r * 8][tx] = v;
  }
  __syncthreads();
  #pragma unroll
  for (int r = 0; r < 4; ++r) {
    int n = n0 + ty + r * 8;
    int k = k0 + tx;
    dst[(size_t)n * 1024 + k] = f2bf(tile[tx][ty + r * 8]);
  }
}

// ---------------- bf16 MFMA GEMM, 128x128 tile, pipelined async staging ----------------
// 3 LDS buffers, prefetch distance 2. Per iter: wait stage k (vmcnt(4): stage
// k+1 stays in flight), raw s_barrier, issue stage k+2, ds_read+MFMA stage k.
// One barrier per iteration; loads remain in flight across it.
// MODE 1: o0=x (bf16), o1=silu(z) (bf16)                         [N=2048]
// MODE 2: o0=delta_raw (bf16), o1=B_ssm (f32), o2=C_ssm (f32)    [N=1152]
// MODE 3: o0=softplus(v + aux[n]) (bf16)                         [N=1024]
// MODE 4: o0=v + aux[m,n] (f32)                                  [N=1024]
template<int MODE>
__global__ __launch_bounds__(256, 3) void gemm_bf(
    const unsigned short* __restrict__ A, const unsigned short* __restrict__ Bt,
    void* __restrict__ o0, void* __restrict__ o1, float* __restrict__ o2f,
    const float* __restrict__ aux) {
  constexpr int NITER = D_MODEL / 32;   // 32
  __shared__ __align__(16) unsigned short a_lds[3][128 * 32];
  __shared__ __align__(16) unsigned short b_lds[3][128 * 32];
  const int tid = threadIdx.x;
  const int m0 = blockIdx.x * 128, n0 = blockIdx.y * 128;
  const int wave = tid >> 6, lane = tid & 63;
  const int wr = (wave >> 1) * 64, wc = (wave & 1) * 64;
  const int lrow = lane & 15, quad = lane >> 4;

  // staging: wave covers rows [wave*32, wave*32+32); 2 instrs of 16 rows each.
  // lane l -> localrow l>>2, slot l&3; global chunk = (l&3) ^ ((l>>3)&3)  (XOR
  // swizzle so frag ds_read_b128 is 2-way bank-aliased = free).
  const int srow = wave * 32 + (lane >> 2);
  const int sc = (lane & 3) ^ ((lane >> 3) & 3);
  const unsigned short* gA  = A  + (size_t)(m0 + srow) * 1024 + sc * 8;
  const unsigned short* gA2 = gA + 16 * 1024;
  const unsigned short* gB  = Bt + (size_t)(n0 + srow) * 1024 + sc * 8;
  const unsigned short* gB2 = gB + 16 * 1024;
  const int soff = wave * 32 * 32;      // wave's staging region (shorts)

  // frag reads: row = (wr|wc) + i*16 + lrow; chunk = quad ^ ((lrow>>1)&3)
  const int q2 = quad ^ ((lrow >> 1) & 3);

  f32x4 acc[4][4];
  #pragma unroll
  for (int i = 0; i < 4; ++i)
    #pragma unroll
    for (int jj = 0; jj < 4; ++jj)
      #pragma unroll
      for (int r = 0; r < 4; ++r) acc[i][jj][r] = 0.f;

  auto issue = [&](int k) {
    unsigned short* ab = &a_lds[k % 3][soff];
    unsigned short* bb = &b_lds[k % 3][soff];
    gload16(gA  + k * 32, ab);
    gload16(gA2 + k * 32, ab + 16 * 32);
    gload16(gB  + k * 32, bb);
    gload16(gB2 + k * 32, bb + 16 * 32);
  };
  auto compute = [&](int k) {
    const unsigned short* ard = &a_lds[k % 3][(wr + lrow) * 32 + q2 * 8];
    const unsigned short* brd = &b_lds[k % 3][(wc + lrow) * 32 + q2 * 8];
    bf16x8 af[4], bfr[4];
    #pragma unroll
    for (int i = 0; i < 4; ++i) {
      af[i]  = *(const bf16x8*)(ard + i * 16 * 32);
      bfr[i] = *(const bf16x8*)(brd + i * 16 * 32);
    }
    #pragma unroll
    for (int i = 0; i < 4; ++i)
      #pragma unroll
      for (int jj = 0; jj < 4; ++jj)
        acc[i][jj] = __builtin_amdgcn_mfma_f32_16x16x32_bf16(af[i], bfr[jj], acc[i][jj], 0, 0, 0);
  };

  issue(0);
  issue(1);
  #pragma unroll
  for (int k = 0; k < NITER - 1; ++k) {
    asm volatile("s_waitcnt vmcnt(4)" ::: "memory");   // stage k landed
    __builtin_amdgcn_s_barrier();
    if (k + 2 < NITER) issue(k + 2);
    compute(k);
  }
  asm volatile("s_waitcnt vmcnt(0)" ::: "memory");
  __builtin_amdgcn_s_barrier();
  compute(NITER - 1);

  // C/D layout: row = quad*4 + r, col = lane&15.
  #pragma unroll
  for (int i = 0; i < 4; ++i) {
    #pragma unroll
    for (int jj = 0; jj < 4; ++jj) {
      #pragma unroll
      for (int r = 0; r < 4; ++r) {
        int m = m0 + wr + i * 16 + quad * 4 + r;
        int n = n0 + wc + jj * 16 + lrow;
        float v = acc[i][jj][r];
        if (MODE == 1) {
          if (n < D_MODEL) {
            ((unsigned short*)o0)[(size_t)m * D_MODEL + n] = f2bf(v);
          } else {
            float sig = 1.f / (1.f + expf(-v));
            ((unsigned short*)o1)[(size_t)m * D_MODEL + (n - D_MODEL)] = f2bf(v * sig);
          }
        } else if (MODE == 2) {
          if (n < D_MODEL)                  ((unsigned short*)o0)[(size_t)m * D_MODEL + n] = f2bf(v);
          else if (n < D_MODEL + D_STATE)   ((float*)o1)[(size_t)m * D_STATE + (n - D_MODEL)] = v;
          else if (n < D_MODEL + 2*D_STATE) o2f[(size_t)m * D_STATE + (n - D_MODEL - D_STATE)] = v;
        } else if (MODE == 3) {
          float t = v + aux[n];
          float sp = (t > 20.f) ? t : log1pf(expf(t));
          ((unsigned short*)o0)[(size_t)m * D_MODEL + n] = f2bf(sp);
        } else {
          ((float*)o0)[(size_t)m * D_MODEL + n] = v + aux[(size_t)m * D_MODEL + n];
        }
      }
    }
  }
}

// ---------------- chunked parallel scan ----------------
template<int PHASE>
__global__ __launch_bounds__(256) void scan_phase(
    const unsigned short* __restrict__ dl_bf, const unsigned short* __restrict__ x_bf,
    const unsigned short* __restrict__ z_bf, const float* __restrict__ Bs,
    const float* __restrict__ Cs, const float* __restrict__ A2g,
    const float* __restrict__ Dpar, const float* __restrict__ hinit,
    float* __restrict__ Hout, float* __restrict__ sdout,
    unsigned short* __restrict__ g) {
  __shared__ float4 bsh[LSEG][4];
  __shared__ float4 csh[LSEG][4];
  const int tid = threadIdx.x;
  const int bid = blockIdx.x;                 // seg(32) x b(4) x dchunk(4) = 512
  const int seg = bid >> 4;
  const int b = (bid >> 2) & 3;
  const int dc = bid & 3;
  const int d = dc * 256 + tid;
  const int t0 = seg * LSEG;
  const int bd = b * D_MODEL + d;

  if (tid < 128) {                            // stage B (and C) segment rows
    int r = tid >> 2, q = tid & 3;
    size_t src = ((size_t)b * SEQ_L + t0 + r) * 4 + q;
    bsh[r][q] = ((const float4*)Bs)[src];
    if (PHASE == 1) csh[r][q] = ((const float4*)Cs)[src];
  }

  float A2r[16];
  {
    const float4* a4 = (const float4*)(A2g + (size_t)d * 16);
    #pragma unroll
    for (int q = 0; q < 4; ++q) {
      float4 v = a4[q];
      A2r[4*q] = v.x; A2r[4*q+1] = v.y; A2r[4*q+2] = v.z; A2r[4*q+3] = v.w;
    }
  }
  float h[16];
  if (PHASE == 1) {
    const float4* h4 = (const float4*)(hinit + (((size_t)seg * 4096) + bd) * 16);
    #pragma unroll
    for (int q = 0; q < 4; ++q) {
      float4 v = h4[q];
      h[4*q] = v.x; h[4*q+1] = v.y; h[4*q+2] = v.z; h[4*q+3] = v.w;
    }
  } else {
    #pragma unroll
    for (int n = 0; n < 16; ++n) h[n] = 0.f;
  }
  const float Dpd = (PHASE == 1) ? Dpar[d] : 0.f;
  float sd = 0.f;
  const size_t base = ((size_t)b * SEQ_L + t0) * D_MODEL + d;
  __syncthreads();

  unsigned short dreg[2][8], xreg[2][8], zreg[2][8];
  #pragma unroll
  for (int t = 0; t < 8; ++t) {
    size_t o = base + (size_t)t * D_MODEL;
    dreg[0][t] = dl_bf[o]; xreg[0][t] = x_bf[o];
    if (PHASE == 1) zreg[0][t] = z_bf[o];
  }
  #pragma unroll
  for (int c = 0; c < LSEG / 8; ++c) {
    const int cur = c & 1, nxt = cur ^ 1;
    if (c < LSEG / 8 - 1) {                   // prefetch next 8 steps
      #pragma unroll
      for (int t = 0; t < 8; ++t) {
        size_t o = base + (size_t)((c + 1) * 8 + t) * D_MODEL;
        dreg[nxt][t] = dl_bf[o]; xreg[nxt][t] = x_bf[o];
        if (PHASE == 1) zreg[nxt][t] = z_bf[o];
      }
    }
    #pragma unroll
    for (int t = 0; t < 8; ++t) {
      const int tt = c * 8 + t;
      float dl = bf2f(dreg[cur][t]);
      float xx = bf2f(xreg[cur][t]);
      float dx = dl * xx;
      sd += dl;
      float4 b0 = bsh[tt][0], b1 = bsh[tt][1], b2 = bsh[tt][2], b3 = bsh[tt][3];
      float bb[16] = {b0.x,b0.y,b0.z,b0.w, b1.x,b1.y,b1.z,b1.w,
                      b2.x,b2.y,b2.z,b2.w, b3.x,b3.y,b3.z,b3.w};
      if (PHASE == 0) {
        #pragma unroll
        for (int n = 0; n < 16; ++n) {
          float dA = exp2f(dl * A2r[n]);
          h[n] = fmaf(dA, h[n], dx * bb[n]);
        }
      } else {
        float4 c0 = csh[tt][0], c1 = csh[tt][1], c2 = csh[tt][2], c3 = csh[tt][3];
        float cc[16] = {c0.x,c0.y,c0.z,c0.w, c1.x,c1.y,c1.z,c1.w,
                        c2.x,c2.y,c2.z,c2.w, c3.x,c3.y,c3.z,c3.w};
        float y = 0.f;
        #pragma unroll
        for (int n = 0; n < 16; ++n) {
          float dA = exp2f(dl * A2r[n]);
          h[n] = fmaf(dA, h[n], dx * bb[n]);
          y = fmaf(h[n], cc[n], y);
        }
        float zz = bf2f(zreg[cur][t]);
        g[base + (size_t)tt * D_MODEL] = f2bf(fmaf(xx, Dpd, y) * zz);
      }
    }
  }
  if (PHASE == 0) {
    float4* ho = (float4*)(Hout + (((size_t)seg * 4096) + bd) * 16);
    #pragma unroll
    for (int q = 0; q < 4; ++q)
      ho[q] = make_float4(h[4*q], h[4*q+1], h[4*q+2], h[4*q+3]);
    sdout[(size_t)seg * 4096 + bd] = sd;
  }
}

// segment-level scan: h_init(s) = P(s-1)*h_init(s-1) + H(s-1), P = exp2(A2*sumdelta)
__global__ __launch_bounds__(256) void scan_phaseB(
    const float* __restrict__ H, const float* __restrict__ sdelta,
    const float* __restrict__ A2g, float* __restrict__ hinit) {
  int gidx = blockIdx.x * 256 + threadIdx.x;   // 65536 = bd(4096) x n(16)
  int bd = gidx >> 4, n = gidx & 15;
  float A2 = A2g[(size_t)(bd & (D_MODEL - 1)) * 16 + n];
  float hp = 0.f;
  #pragma unroll
  for (int s = 0; s < NSEG; ++s) {
    size_t idx = ((size_t)s * 4096 + bd) * 16 + n;
    hinit[idx] = hp;
    float P = exp2f(A2 * sdelta[(size_t)s * 4096 + bd]);
    hp = fmaf(P, hp, H[idx]);
  }
}

// ---------------- LayerNorm over D=1024 per row ----------------
__global__ __launch_bounds__(256) void ln_kernel(const float* __restrict__ res,
    const float* __restrict__ lng, const float* __restrict__ lnb,
    void* __restrict__ out, const int* __restrict__ flag) {
  int row = blockIdx.x, tid = threadIdx.x;
  const float4* r4 = (const float4*)(res + (size_t)row * D_MODEL);
  float4 v = r4[tid];
  float s = v.x + v.y + v.z + v.w;
  float q = v.x * v.x + v.y * v.y + v.z * v.z + v.w * v.w;
  #pragma unroll
  for (int m = 1; m < 64; m <<= 1) { s += __shfl_xor(s, m); q += __shfl_xor(q, m); }
  __shared__ float ss[4], qs[4];
  int w = tid >> 6;
  if ((tid & 63) == 0) { ss[w] = s; qs[w] = q; }
  __syncthreads();
  s = ss[0] + ss[1] + ss[2] + ss[3];
  q = qs[0] + qs[1] + qs[2] + qs[3];
  float mu = s * (1.f / D_MODEL);
  float var = q * (1.f / D_MODEL) - mu * mu;
  float rstd = rsqrtf(var + 1e-5f);
  float4 gg = ((const float4*)lng)[tid];
  float4 bb = ((const float4*)lnb)[tid];
  float o0 = (v.x - mu) * rstd * gg.x + bb.x;
  float o1 = (v.y - mu) * rstd * gg.y + bb.y;
  float o2 = (v.z - mu) * rstd * gg.z + bb.z;
  float o3 = (v.w - mu) * rstd * gg.w + bb.w;
  if (*flag) {
    ushort4 pv;
    pv.x = f2bf(o0); pv.y = f2bf(o1); pv.z = f2bf(o2); pv.w = f2bf(o3);
    ((ushort4*)out)[(size_t)row * 256 + tid] = pv;
  } else {
    ((float4*)out)[(size_t)row * 256 + tid] = make_float4(o0, o1, o2, o3);
  }
}

extern "C" void kernel_launch(void* const* d_in, const int* in_sizes, int n_in,
                              void* d_out, int out_size, void* d_ws, size_t ws_size,
                              hipStream_t stream) {
  (void)in_sizes; (void)n_in; (void)out_size; (void)ws_size;
  const void* x_in  = d_in[0];
  const void* W_in  = d_in[1];
  const void* W_x   = d_in[2];
  const void* W_dt  = d_in[3];
  const void* b_dt  = d_in[4];
  const void* A_log = d_in[5];
  const void* D_par = d_in[6];
  const void* W_out = d_in[7];
  const void* ln_g  = d_in[8];
  const void* ln_b  = d_in[9];

  char* ws = (char*)d_ws;
  size_t off = 0;
  auto alloc = [&](size_t bytes) -> void* {
    void* p = ws + off;
    off += (bytes + 255) & ~(size_t)255;
    return p;
  };
  int* flag              = (int*)alloc(16);
  float* x_in_f          = (float*)alloc((size_t)M_ROWS * D_MODEL * 4);
  unsigned short* x_in_b = (unsigned short*)alloc((size_t)M_ROWS * D_MODEL * 2);
  float* bdt_f           = (float*)alloc(1024 * 4);
  float* a2_f            = (float*)alloc(16384 * 4);
  float* dp_f            = (float*)alloc(1024 * 4);
  float* lng_f           = (float*)alloc(1024 * 4);
  float* lnb_f           = (float*)alloc(1024 * 4);
  unsigned short* wt_in  = (unsigned short*)alloc((size_t)2048 * 1024 * 2);
  unsigned short* wt_x   = (unsigned short*)alloc((size_t)1152 * 1024 * 2);
  unsigned short* wt_dt  = (unsigned short*)alloc((size_t)1024 * 1024 * 2);
  unsigned short* wt_out = (unsigned short*)alloc((size_t)1024 * 1024 * 2);
  unsigned short* x_bf   = (unsigned short*)alloc((size_t)M_ROWS * D_MODEL * 2);
  unsigned short* s_bf   = (unsigned short*)alloc((size_t)M_ROWS * D_MODEL * 2);  // silu(z)
  unsigned short* draw_bf= (unsigned short*)alloc((size_t)M_ROWS * D_MODEL * 2);
  unsigned short* delta_bf=(unsigned short*)alloc((size_t)M_ROWS * D_MODEL * 2);
  float* bssm_f          = (float*)alloc((size_t)M_ROWS * D_STATE * 4);
  float* cssm_f          = (float*)alloc((size_t)M_ROWS * D_STATE * 4);
  float* H_f             = (float*)alloc((size_t)NSEG * 4096 * 16 * 4);
  float* hinit_f         = (float*)alloc((size_t)NSEG * 4096 * 16 * 4);
  float* sdelta_f        = (float*)alloc((size_t)NSEG * 4096 * 4);
  unsigned short* g_bf = draw_bf;   // alias: draw consumed by GEMM3 before scanC writes g
  float* res_f = (float*)x_bf;      // alias: x_bf+s_bf (16MB contiguous) consumed by scanC
                                    // before GEMM4 writes res

  detect_kernel<<<1, 256, 0, stream>>>((const unsigned short*)x_in, flag);
  convert_x_kernel<<<2048, 256, 0, stream>>>(x_in, x_in_f, x_in_b, flag);
  convert_smalls_kernel<<<80, 256, 0, stream>>>(b_dt, A_log, D_par, ln_g, ln_b,
                                                bdt_f, a2_f, dp_f, lng_f, lnb_f, flag);
  dim3 tb(32, 8);
  transpose_w_kernel<<<dim3(64, 32), tb, 0, stream>>>(W_in,  wt_in,  2048, flag);
  transpose_w_kernel<<<dim3(36, 32), tb, 0, stream>>>(W_x,   wt_x,   1056, flag);
  transpose_w_kernel<<<dim3(32, 32), tb, 0, stream>>>(W_dt,  wt_dt,  1024, flag);
  transpose_w_kernel<<<dim3(32, 32), tb, 0, stream>>>(W_out, wt_out, 1024, flag);

  gemm_bf<1><<<dim3(32, 16), 256, 0, stream>>>(x_in_b, wt_in, x_bf, s_bf, nullptr, nullptr);
  gemm_bf<2><<<dim3(32, 9),  256, 0, stream>>>(x_bf, wt_x, draw_bf, bssm_f, cssm_f, nullptr);
  gemm_bf<3><<<dim3(32, 8),  256, 0, stream>>>(draw_bf, wt_dt, delta_bf, nullptr, nullptr, bdt_f);

  scan_phase<0><<<512, 256, 0, stream>>>(delta_bf, x_bf, nullptr, bssm_f, nullptr,
                                         a2_f, nullptr, nullptr, H_f, sdelta_f, nullptr);
  scan_phaseB<<<256, 256, 0, stream>>>(H_f, sdelta_f, a2_f, hinit_f);
  scan_phase<1><<<512, 256, 0, stream>>>(delta_bf, x_bf, s_bf, bssm_f, cssm_f,
                                         a2_f, dp_f, hinit_f, nullptr, nullptr, g_bf);

  gemm_bf<4><<<dim3(32, 8),  256, 0, stream>>>(g_bf, wt_out, res_f, nullptr, nullptr, x_in_f);
  ln_kernel<<<4096, 256, 0, stream>>>(res_f, lng_f, lnb_f, d_out, flag);
}